// Round 1
// baseline (424.824 us; speedup 1.0000x reference)
//
#include <hip/hip_runtime.h>

#define BATCH 16
#define NV    20000
#define FIN   64
#define NCOUT 64
#define NK    16
#define TOTROWS (BATCH * NV)

// One wave (64 lanes) per output row (b,v). lane = output column c for the
// matmul accumulate, lane = feature f for the gather accumulate; the nbsum
// vector makes one LDS round-trip to transpose between the two views.
// Weight columns live in 128 VGPRs per wave, reused across ~78 rows
// (grid-stride persistent waves).
__global__ __launch_bounds__(256, 2) void convnet_fused(
    const float* __restrict__ x,     // (B, V, 64)
    const float* __restrict__ Wx,    // (64, 64)
    const float* __restrict__ Wn,    // (64, 64)
    const float* __restrict__ bias,  // (64)
    const int*   __restrict__ nbr,   // (V, 16), values in [0, V]; 0 = zero pad
    float*       __restrict__ out)   // (B, V, 64)
{
    __shared__ __align__(16) float sn[4][FIN];

    const int lane = threadIdx.x & 63;
    const int wave = threadIdx.x >> 6;

    // Per-lane weight columns: wx[f] = Wx[f][lane]; Wn pre-scaled by 1/16
    // so nbsum (not nbmean) feeds the matmul directly.
    float wx[FIN], wn[FIN];
#pragma unroll
    for (int f = 0; f < FIN; ++f) {
        wx[f] = Wx[f * NCOUT + lane];
        wn[f] = Wn[f * NCOUT + lane] * (1.0f / 16.0f);
    }
    const float bias_r = bias[lane];

    const int nwaves = (gridDim.x * blockDim.x) >> 6;
    const int gw = (blockIdx.x * blockDim.x + threadIdx.x) >> 6;

    float* snw = &sn[wave][0];

    for (int row = gw; row < TOTROWS; row += nwaves) {
        // Force wave-uniformity so neighbor-index loads and the x-row loads
        // scalarize (s_load) and gather addresses become saddr + lane*4.
        const int rowu = __builtin_amdgcn_readfirstlane(row);
        const int b = rowu / NV;
        const int v = rowu - b * NV;
        const float* xb   = x + (size_t)b * (NV * FIN);
        const float* xrow = xb + (size_t)v * FIN;
        const int*   nbrow = nbr + (size_t)v * NK;

        // Gather-sum of neighbor rows, lane = feature f.
        // idx==0 means the zero-pad row: always load (clamped to row 0,
        // valid memory) and mask the add — keeps all 16 loads in flight.
        float nbs = 0.0f;
#pragma unroll
        for (int k = 0; k < NK; ++k) {
            const int idx = nbrow[k];
            int sel = idx - 1;
            sel = sel < 0 ? 0 : sel;
            const float val = xb[(size_t)sel * FIN + lane];
            nbs += (idx != 0) ? val : 0.0f;
        }

        // Transpose nbsum through LDS: write lane=f view, read as float4
        // broadcasts (all lanes same address -> conflict-free broadcast).
        snw[lane] = nbs;
        __builtin_amdgcn_wave_barrier();  // keep write before reads in sched

        float acc0 = bias_r, acc1 = 0.0f, acc2 = 0.0f, acc3 = 0.0f;
        const float4* xr4 = (const float4*)xrow;   // uniform address -> s_load
        const float4* nr4 = (const float4*)snw;
#pragma unroll
        for (int q = 0; q < FIN / 4; ++q) {
            const float4 aq = xr4[q];
            const float4 nq = nr4[q];
            acc0 = fmaf(aq.x, wx[4 * q + 0], acc0);
            acc1 = fmaf(aq.y, wx[4 * q + 1], acc1);
            acc2 = fmaf(aq.z, wx[4 * q + 2], acc2);
            acc3 = fmaf(aq.w, wx[4 * q + 3], acc3);
            acc0 = fmaf(nq.x, wn[4 * q + 0], acc0);
            acc1 = fmaf(nq.y, wn[4 * q + 1], acc1);
            acc2 = fmaf(nq.z, wn[4 * q + 2], acc2);
            acc3 = fmaf(nq.w, wn[4 * q + 3], acc3);
        }
        out[(size_t)rowu * NCOUT + lane] = (acc0 + acc1) + (acc2 + acc3);
    }
}

extern "C" void kernel_launch(void* const* d_in, const int* in_sizes, int n_in,
                              void* d_out, int out_size, void* d_ws, size_t ws_size,
                              hipStream_t stream) {
    const float* x    = (const float*)d_in[0];
    const float* Wx   = (const float*)d_in[1];
    const float* Wn   = (const float*)d_in[2];
    const float* bias = (const float*)d_in[3];
    const int*   nbr  = (const int*)d_in[4];
    float* out = (float*)d_out;

    dim3 grid(1024), block(256);
    hipLaunchKernelGGL(convnet_fused, grid, block, 0, stream,
                       x, Wx, Wn, bias, nbr, out);
}

// Round 2
// 359.904 us; speedup vs baseline: 1.1804x; 1.1804x over previous
//
#include <hip/hip_runtime.h>
#include <hip/hip_bf16.h>

#define BATCH 16
#define NV    20000
#define FIN   64
#define NCOUT 64
#define NK    16
#define TOTROWS (BATCH * NV)

// Grid geometry shared by both passes: 2048 blocks x 256 threads.
// blockIdx % 8 ~ XCD (round-robin dispatch heuristic); XCD j owns batches
// {2j, 2j+1} so its 4 MiB L2 holds one 2.56 MB bf16 gather window at a time.
#define NBLOCKS 2048

// ---------------------------------------------------------------------------
// Pass 1: z[b,v,c] = sum_f x[b,v,f] * Wn[f,c] / 16, stored bf16.
// One wave per row; x row read via wave-uniform s_load broadcasts; Wn column
// per lane in 64 VGPRs.
// ---------------------------------------------------------------------------
__global__ __launch_bounds__(256, 2) void convnet_pass1_z(
    const float* __restrict__ x,      // (B, V, 64) fp32
    const float* __restrict__ Wn,     // (64, 64)
    __hip_bfloat16* __restrict__ z)   // (B, V, 64) bf16, workspace
{
    const int lane = threadIdx.x & 63;

    float wn[FIN];
#pragma unroll
    for (int f = 0; f < FIN; ++f)
        wn[f] = Wn[f * NCOUT + lane] * (1.0f / 16.0f);

    const int xcd = blockIdx.x & 7;
    const int bi  = blockIdx.x >> 3;                       // block within XCD
    const int wl  = (bi * blockDim.x + threadIdx.x) >> 6;  // wave within XCD
    const int wpx = (NBLOCKS >> 3) * (256 >> 6);           // waves per XCD = 1024
    const int rows_per_xcd = 2 * NV;                       // two batches
    const int base = xcd * rows_per_xcd;

    for (int r = wl; r < rows_per_xcd; r += wpx) {
        const int rowu = __builtin_amdgcn_readfirstlane(base + r);
        const float4* xr4 = (const float4*)(x + (size_t)rowu * FIN);
        float a0 = 0.f, a1 = 0.f, a2 = 0.f, a3 = 0.f;
#pragma unroll
        for (int q = 0; q < FIN / 4; ++q) {
            const float4 a = xr4[q];
            a0 = fmaf(a.x, wn[4 * q + 0], a0);
            a1 = fmaf(a.y, wn[4 * q + 1], a1);
            a2 = fmaf(a.z, wn[4 * q + 2], a2);
            a3 = fmaf(a.w, wn[4 * q + 3], a3);
        }
        z[(size_t)rowu * NCOUT + lane] = __float2bfloat16((a0 + a1) + (a2 + a3));
    }
}

// ---------------------------------------------------------------------------
// Pass 2: out[b,v,c] = x[b,v,:]@Wx[:,c] + bias[c] + sum_k z[b, nbr[v,k]-1, c]
// (idx==0 is the zero pad -> masked add). Gather is lane=c directly: no
// transpose. 16 independent 128 B bf16 gathers per row, mostly L2-resident.
// ---------------------------------------------------------------------------
__global__ __launch_bounds__(256, 2) void convnet_pass2_out(
    const float* __restrict__ x,          // (B, V, 64) fp32
    const float* __restrict__ Wx,         // (64, 64)
    const float* __restrict__ bias,       // (64)
    const int*   __restrict__ nbr,        // (V, 16), values in [0, V]
    const __hip_bfloat16* __restrict__ z, // (B, V, 64) bf16
    float*       __restrict__ out)        // (B, V, 64) fp32
{
    const int lane = threadIdx.x & 63;

    float wx[FIN];
#pragma unroll
    for (int f = 0; f < FIN; ++f)
        wx[f] = Wx[f * NCOUT + lane];
    const float bias_r = bias[lane];

    const int xcd = blockIdx.x & 7;
    const int bi  = blockIdx.x >> 3;
    const int wl  = (bi * blockDim.x + threadIdx.x) >> 6;
    const int wpx = (NBLOCKS >> 3) * (256 >> 6);           // 1024 waves/XCD
    const int rows_per_xcd = 2 * NV;
    const int base = xcd * rows_per_xcd;

    for (int r = wl; r < rows_per_xcd; r += wpx) {
        const int rowu = __builtin_amdgcn_readfirstlane(base + r);
        // batch-major within the XCD's two batches; avoid integer div
        const int in_b1 = (r >= NV) ? 1 : 0;
        const int b = 2 * xcd + in_b1;
        const int v = r - in_b1 * NV;

        const int* nbrow = nbr + (size_t)v * NK;
        const __hip_bfloat16* zb = z + (size_t)b * (NV * NCOUT);

        // Gather-sum of 16 bf16 z-rows, lane = output column c.
        float g0 = 0.f, g1 = 0.f, g2 = 0.f, g3 = 0.f;
#pragma unroll
        for (int k = 0; k < NK; ++k) {
            const int idx = nbrow[k];          // uniform -> s_load
            int sel = idx - 1;
            sel = sel < 0 ? 0 : sel;           // clamp pad to valid memory
            const float val =
                __bfloat162float(zb[(size_t)sel * NCOUT + lane]);
            const float m = (idx != 0) ? val : 0.0f;
            if ((k & 3) == 0) g0 += m;
            else if ((k & 3) == 1) g1 += m;
            else if ((k & 3) == 2) g2 += m;
            else g3 += m;
        }

        // x @ Wx via uniform float4 broadcasts of the x row.
        const float4* xr4 = (const float4*)(x + (size_t)rowu * FIN);
        float a0 = bias_r + g0, a1 = g1, a2 = g2, a3 = g3;
#pragma unroll
        for (int q = 0; q < FIN / 4; ++q) {
            const float4 a = xr4[q];
            a0 = fmaf(a.x, wx[4 * q + 0], a0);
            a1 = fmaf(a.y, wx[4 * q + 1], a1);
            a2 = fmaf(a.z, wx[4 * q + 2], a2);
            a3 = fmaf(a.w, wx[4 * q + 3], a3);
        }
        out[(size_t)rowu * NCOUT + lane] = (a0 + a1) + (a2 + a3);
    }
}

extern "C" void kernel_launch(void* const* d_in, const int* in_sizes, int n_in,
                              void* d_out, int out_size, void* d_ws, size_t ws_size,
                              hipStream_t stream) {
    const float* x    = (const float*)d_in[0];
    const float* Wx   = (const float*)d_in[1];
    const float* Wn   = (const float*)d_in[2];
    const float* bias = (const float*)d_in[3];
    const int*   nbr  = (const int*)d_in[4];
    float* out = (float*)d_out;

    // Workspace: z is B*V*64 bf16 = 40.96 MB.
    __hip_bfloat16* z = (__hip_bfloat16*)d_ws;

    dim3 grid(NBLOCKS), block(256);
    hipLaunchKernelGGL(convnet_pass1_z, grid, block, 0, stream, x, Wn, z);
    hipLaunchKernelGGL(convnet_pass2_out, grid, block, 0, stream,
                       x, Wx, bias, nbr, z, out);
}